// Round 15
// baseline (998.136 us; speedup 1.0000x reference)
//
#include <hip/hip_runtime.h>
#include <math.h>
#include <type_traits>

// SelfAttention B=4,S=4096,H=1024 fp32 — MFMA, fp16-split precision.
// R15 = R14 + counted-vmcnt depth-1 on projqk (2x32KB) and depth-2 on pv
// (3x24KB, vmcnt(6)). scores/projv stay depth-1 (K=1024 proven optimum).

typedef unsigned short u16;
typedef _Float16 f16x8 __attribute__((ext_vector_type(8)));
typedef __bf16 bf16x8 __attribute__((ext_vector_type(8)));
typedef float f32x4 __attribute__((ext_vector_type(4)));
struct __align__(8) u16x4 { u16 x, y, z, w; };

__device__ __forceinline__ u16 f2bf(float f) {
    unsigned u = __builtin_bit_cast(unsigned, f);
    u += 0x7fffu + ((u >> 16) & 1u);
    return (u16)(u >> 16);
}
__device__ __forceinline__ u16 f2h(float f) {
    _Float16 h = (_Float16)f;
    return __builtin_bit_cast(u16, h);
}
__device__ __forceinline__ float h2f(u16 h) {
    return (float)__builtin_bit_cast(_Float16, h);
}

#define MF16(a, b, c) __builtin_amdgcn_mfma_f32_16x16x32_f16( \
    __builtin_bit_cast(f16x8, a), __builtin_bit_cast(f16x8, b), c, 0, 0, 0)
#define MBF16(a, b, c) __builtin_amdgcn_mfma_f32_16x16x32_bf16(a, b, c, 0, 0, 0)

// Batch-blocked q/k/P region geometry (u16 elements).
#define SLOT_E  (4u * 1024 * 1024)        // 8 MiB
#define BBLK_E  (16u * 1024 * 1024)       // 32 MiB per batch block

// ---------------- fused q+k projection, counted-vmcnt depth-1 ----------------
// 512 thr = 8 waves; waves 0-3 q-tile, 4-7 k-tile; shared {xh,xl} A-tiles.
// Buffer = {xh,xl,Wq,Wk}[128][32] = 32KB; 2 buffers = 64KB; 4 loads/wave.
__global__ __launch_bounds__(512, 4) void gemm_projqk(
    const u16* __restrict__ xh, const u16* __restrict__ xl,
    const u16* __restrict__ Wq, const u16* __restrict__ Wk,
    const float* __restrict__ bq, const float* __restrict__ bk,
    u16* __restrict__ qout, u16* __restrict__ kout)
{
    __shared__ char lds[2 * 32768];
    const int K = 1024, lda = 1024, ldb = 1024, ldc = 1024, nbx = 8;

    const int cpx = (int)gridDim.x >> 3;
    const int raw = blockIdx.x;
    const int swz = (raw & 7) * cpx + (raw >> 3);
    const int bm = (swz / nbx) * 128, bn = (swz % nbx) * 128;

    const int t = threadIdx.x;
    const int w = t >> 6, lane = t & 63;
    const int qksel = w >> 2;
    const int wl = w & 3;
    const int wr = wl >> 1, wc = wl & 1;
    const int r16 = lane & 15, g = lane >> 4;

    f32x4 acc[4][4];
#pragma unroll
    for (int i = 0; i < 4; ++i)
#pragma unroll
        for (int j = 0; j < 4; ++j) acc[i][j] = (f32x4)0.0f;

    auto STAGE = [&](auto BO, int k0) {
#pragma unroll
        for (int i = 0; i < 4; ++i) {
            constexpr int bufo = decltype(BO)::value;
            const int ch = w * 4 + i;            // 0..31
            const int tt = ch >> 3, sub = ch & 7;
            const int s = sub * 64 + lane;
            const int row = s >> 2;
            const int kg = (s & 3) ^ ((row >> 1) & 3);
            const u16* P = (tt == 0) ? xh : (tt == 1) ? xl : (tt == 2) ? Wq : Wk;
            const int rbase = (tt < 2) ? bm : bn;
            const int ld = (tt < 2) ? lda : ldb;
            __builtin_amdgcn_global_load_lds(
                (const __attribute__((address_space(1))) void*)
                    (P + (size_t)(rbase + row) * ld + k0 + kg * 8),
                (__attribute__((address_space(3))) void*)(lds + bufo + ch * 1024),
                16, 0, 0);
        }
    };

    bf16x8 fa[2][4], fb[4];
    auto FRAGS = [&](auto BO) {
        constexpr int bufo = decltype(BO)::value;
#pragma unroll
        for (int i = 0; i < 4; ++i) {
            const int ra = wr * 64 + i * 16 + r16;
            const int oa = ra * 64 + ((g ^ ((ra >> 1) & 3)) << 4);
            fa[0][i] = *(const bf16x8*)(lds + bufo + oa);
            fa[1][i] = *(const bf16x8*)(lds + bufo + 8192 + oa);
            const int rbw = wc * 64 + i * 16 + r16;
            const int ob = rbw * 64 + ((g ^ ((rbw >> 1) & 3)) << 4);
            fb[i] = *(const bf16x8*)(lds + bufo + (2 + qksel) * 8192 + ob);
        }
    };
    auto MM = [&]() {
#pragma unroll
        for (int i = 0; i < 4; ++i)
#pragma unroll
            for (int j = 0; j < 4; ++j) {
                acc[i][j] = MF16(fa[0][i], fb[j], acc[i][j]);
                acc[i][j] = MF16(fa[1][i], fb[j], acc[i][j]);
            }
    };

    std::integral_constant<int, 0> c0;
    std::integral_constant<int, 32768> c1;

    const int nk = K >> 5;                 // 32
    STAGE(c0, 0);
    STAGE(c1, 1 << 5);
    for (int tt = 0; tt + 2 < nk; tt += 2) {
        asm volatile("s_waitcnt vmcnt(4)\n\ts_barrier" ::: "memory");
        FRAGS(c0);
        asm volatile("s_waitcnt lgkmcnt(0)\n\ts_barrier" ::: "memory");
        STAGE(c0, (tt + 2) << 5);
        MM();
        asm volatile("s_waitcnt vmcnt(4)\n\ts_barrier" ::: "memory");
        FRAGS(c1);
        asm volatile("s_waitcnt lgkmcnt(0)\n\ts_barrier" ::: "memory");
        STAGE(c1, (tt + 3) << 5);
        MM();
    }
    asm volatile("s_waitcnt vmcnt(4)\n\ts_barrier" ::: "memory");
    FRAGS(c0);
    MM();
    asm volatile("s_waitcnt vmcnt(0)\n\ts_barrier" ::: "memory");
    FRAGS(c1);
    MM();

    u16* Cout = qksel ? kout : qout;
    const float* bias = qksel ? bk : bq;
#pragma unroll
    for (int j = 0; j < 4; ++j) {
        const int gc = bn + wc * 64 + j * 16 + r16;
        const float bv = bias[gc];
#pragma unroll
        for (int i = 0; i < 4; ++i) {
            const int gr = bm + wr * 64 + i * 16 + g * 4;
#pragma unroll
            for (int r = 0; r < 4; ++r) {
                const int grr = gr + r;
                const size_t bb = (size_t)(grr >> 12) * BBLK_E;
                Cout[bb + (size_t)(grr & 4095) * ldc + gc] = f2h(acc[i][j][r] + bv);
            }
        }
    }
}

#define GEMM_PARAMS const u16* __restrict__ A0, const u16* __restrict__ B0, \
    int K, int lda, int ldb, const float* __restrict__ bias, \
    float* __restrict__ Cf, u16* __restrict__ Ch, \
    int ldc, int nbx, unsigned long long zsA, unsigned long long zsB, \
    unsigned long long zsC

// ---------- 8-wave 128x256 1-product GEMM, counted-vmcnt depth 1 or 2 ----------
// Buffer = A[128][32] 8KB + B[256][32] 16KB = 24KB. Stage = 3 loads/wave.
// DEPTH=1: 2 buffers, vmcnt(3). DEPTH=2: 3 buffers, vmcnt(6), tail vmcnt(3)/0.
template<int VAR, int DEPTH>  // VAR 1: projv f16->bf16^T+bias; 2: scores f16->f32; 3: pv bf16->f32
__device__ __forceinline__ void gemm8_body(GEMM_PARAMS)
{
    __shared__ char lds[(DEPTH + 1) * 24576];

    const int cpx = (int)gridDim.x >> 3;
    const int raw = blockIdx.x;
    const int swz = (raw & 7) * cpx + (raw >> 3);
    const int bm = (swz / nbx) * 128, bn = (swz % nbx) * 256;

    const unsigned long long z = blockIdx.z;
    A0 += z * zsA;
    B0 += z * zsB;

    const int t = threadIdx.x;
    const int w = t >> 6, lane = t & 63;
    const int wr = w >> 2, wc = w & 3;
    const int r16 = lane & 15, g = lane >> 4;

    f32x4 acc[4][4];
#pragma unroll
    for (int i = 0; i < 4; ++i)
#pragma unroll
        for (int j = 0; j < 4; ++j) acc[i][j] = (f32x4)0.0f;

    auto STAGE = [&](auto BO, int k0) {
#pragma unroll
        for (int i = 0; i < 3; ++i) {
            constexpr int bufo = decltype(BO)::value;
            const int ch = w * 3 + i;             // 0..23; 0-7 A, 8-23 B
            const int isB = (ch >= 8);
            const int cb = isB ? (ch - 8) : ch;
            const int row = cb * 16 + (lane >> 2);
            const int kg = (lane & 3) ^ ((row >> 1) & 3);
            const u16* P = isB ? B0 : A0;
            const int rbase = isB ? bn : bm;
            const int ld = isB ? ldb : lda;
            __builtin_amdgcn_global_load_lds(
                (const __attribute__((address_space(1))) void*)
                    (P + (size_t)(rbase + row) * ld + k0 + kg * 8),
                (__attribute__((address_space(3))) void*)
                    (lds + bufo + (isB ? 8192 : 0) + cb * 1024),
                16, 0, 0);
        }
    };

    bf16x8 fa[4], fb[4];
    auto FRAGS = [&](auto BO) {
        constexpr int bufo = decltype(BO)::value;
#pragma unroll
        for (int i = 0; i < 4; ++i) {
            const int ra = wr * 64 + i * 16 + r16;
            fa[i] = *(const bf16x8*)(lds + bufo + ra * 64 + ((g ^ ((ra >> 1) & 3)) << 4));
            const int rb = wc * 64 + i * 16 + r16;
            fb[i] = *(const bf16x8*)(lds + bufo + 8192 + rb * 64 + ((g ^ ((rb >> 1) & 3)) << 4));
        }
    };
    auto MM = [&]() {
#pragma unroll
        for (int i = 0; i < 4; ++i)
#pragma unroll
            for (int j = 0; j < 4; ++j) {
                if constexpr (VAR == 3) acc[i][j] = MBF16(fa[i], fb[j], acc[i][j]);
                else                    acc[i][j] = MF16(fa[i], fb[j], acc[i][j]);
            }
    };

    std::integral_constant<int, 0> c0;
    std::integral_constant<int, 24576> c1;
    std::integral_constant<int, 49152> c2;

    const int nk = K >> 5;                 // 32 (projv/scores) or 128 (pv)

    if constexpr (DEPTH == 1) {
        STAGE(c0, 0);
        STAGE(c1, 1 << 5);
        for (int tt = 0; tt + 2 < nk; tt += 2) {
            asm volatile("s_waitcnt vmcnt(3)\n\ts_barrier" ::: "memory");
            FRAGS(c0);
            asm volatile("s_waitcnt lgkmcnt(0)\n\ts_barrier" ::: "memory");
            STAGE(c0, (tt + 2) << 5);
            MM();
            asm volatile("s_waitcnt vmcnt(3)\n\ts_barrier" ::: "memory");
            FRAGS(c1);
            asm volatile("s_waitcnt lgkmcnt(0)\n\ts_barrier" ::: "memory");
            STAGE(c1, (tt + 3) << 5);
            MM();
        }
        asm volatile("s_waitcnt vmcnt(3)\n\ts_barrier" ::: "memory");
        FRAGS(c0);
        MM();
        asm volatile("s_waitcnt vmcnt(0)\n\ts_barrier" ::: "memory");
        FRAGS(c1);
        MM();
    } else {
        // depth-2: 3 buffers; steady outstanding = 2 stages = 6 loads.
        STAGE(c0, 0);
        STAGE(c1, 1 << 5);
        STAGE(c2, 2 << 5);
        for (int tt = 0; tt + 4 < nk; tt += 3) {
            asm volatile("s_waitcnt vmcnt(6)\n\ts_barrier" ::: "memory");
            FRAGS(c0);
            asm volatile("s_waitcnt lgkmcnt(0)\n\ts_barrier" ::: "memory");
            STAGE(c0, (tt + 3) << 5);
            MM();
            asm volatile("s_waitcnt vmcnt(6)\n\ts_barrier" ::: "memory");
            FRAGS(c1);
            asm volatile("s_waitcnt lgkmcnt(0)\n\ts_barrier" ::: "memory");
            STAGE(c1, (tt + 4) << 5);
            MM();
            asm volatile("s_waitcnt vmcnt(6)\n\ts_barrier" ::: "memory");
            FRAGS(c2);
            asm volatile("s_waitcnt lgkmcnt(0)\n\ts_barrier" ::: "memory");
            if (tt + 5 < nk) STAGE(c2, (tt + 5) << 5);
            MM();
        }
        // tail: iters nk-2 (c0; stage nk-1 = 3 loads in flight), nk-1 (c1)
        asm volatile("s_waitcnt vmcnt(3)\n\ts_barrier" ::: "memory");
        FRAGS(c0);
        MM();
        asm volatile("s_waitcnt vmcnt(0)\n\ts_barrier" ::: "memory");
        FRAGS(c1);
        MM();
    }

    // ---- epilogue: C/D layout col=lane&15, row=(lane>>4)*4+reg ----
#pragma unroll
    for (int j = 0; j < 4; ++j) {
        const int gc = bn + wc * 64 + j * 16 + r16;
        const float bv = bias ? bias[gc] : 0.0f;
#pragma unroll
        for (int i = 0; i < 4; ++i) {
            const int gr = bm + wr * 64 + i * 16 + g * 4;
#pragma unroll
            for (int r = 0; r < 4; ++r) {
                const float val = acc[i][j][r] + bv;
                const int grr = gr + r;
                if constexpr (VAR == 1) {
                    Ch[(size_t)gc * ldc + grr] = f2bf(val);   // transposed
                } else {
                    Cf[z * zsC + (size_t)grr * ldc + gc] = val;
                }
            }
        }
    }
}

__global__ __launch_bounds__(512, 4) void gemm_projv(GEMM_PARAMS) { gemm8_body<1, 1>(A0,B0,K,lda,ldb,bias,Cf,Ch,ldc,nbx,zsA,zsB,zsC); }
__global__ __launch_bounds__(512, 4) void gemm_scores(GEMM_PARAMS){ gemm8_body<2, 1>(A0,B0,K,lda,ldb,bias,Cf,Ch,ldc,nbx,zsA,zsB,zsC); }
__global__ __launch_bounds__(512, 4) void gemm_pv(GEMM_PARAMS)    { gemm8_body<3, 2>(A0,B0,K,lda,ldb,bias,Cf,Ch,ldc,nbx,zsA,zsB,zsC); }

// fp32 -> fp16 (hi, lo) elementwise over float4 groups.
__global__ __launch_bounds__(256) void split_h(
    const float* __restrict__ in, u16* __restrict__ hi, u16* __restrict__ lo, int n4)
{
    const int i = blockIdx.x * 256 + threadIdx.x;
    if (i >= n4) return;
    const float4 v = ((const float4*)in)[i];
    u16x4 h, l;
    h.x = f2h(v.x); l.x = f2h(v.x - h2f(h.x));
    h.y = f2h(v.y); l.y = f2h(v.y - h2f(h.y));
    h.z = f2h(v.z); l.z = f2h(v.z - h2f(h.z));
    h.w = f2h(v.w); l.w = f2h(v.w - h2f(h.w));
    ((u16x4*)hi)[i] = h;
    ((u16x4*)lo)[i] = l;
}

// Row softmax over 4096 fp32 -> bf16 P. One 256-thread block per row.
__global__ __launch_bounds__(256) void softmax4096(
    const float* __restrict__ S, u16* __restrict__ P)
{
    const float* p = S + (size_t)blockIdx.x * 4096;
    u16* q = P + (size_t)blockIdx.x * 4096;
    const int t = threadIdx.x;
    const int wave = t >> 6, lane = t & 63;
    __shared__ float red[8];

    float4 v[4];
    float mx = -INFINITY;
#pragma unroll
    for (int i = 0; i < 4; ++i) {
        v[i] = ((const float4*)p)[i * 256 + t];
        mx = fmaxf(mx, fmaxf(fmaxf(v[i].x, v[i].y), fmaxf(v[i].z, v[i].w)));
    }
#pragma unroll
    for (int o = 32; o > 0; o >>= 1) mx = fmaxf(mx, __shfl_xor(mx, o));
    if (lane == 0) red[wave] = mx;
    __syncthreads();
    mx = fmaxf(fmaxf(red[0], red[1]), fmaxf(red[2], red[3]));

    float sum = 0.f;
#pragma unroll
    for (int i = 0; i < 4; ++i) {
        v[i].x = __expf(v[i].x - mx);
        v[i].y = __expf(v[i].y - mx);
        v[i].z = __expf(v[i].z - mx);
        v[i].w = __expf(v[i].w - mx);
        sum += (v[i].x + v[i].y) + (v[i].z + v[i].w);
    }
#pragma unroll
    for (int o = 32; o > 0; o >>= 1) sum += __shfl_xor(sum, o);
    if (lane == 0) red[4 + wave] = sum;
    __syncthreads();
    sum = (red[4] + red[5]) + (red[6] + red[7]);

    const float inv = 1.0f / sum;
#pragma unroll
    for (int i = 0; i < 4; ++i) {
        u16x4 u;
        u.x = f2bf(v[i].x * inv); u.y = f2bf(v[i].y * inv);
        u.z = f2bf(v[i].z * inv); u.w = f2bf(v[i].w * inv);
        ((u16x4*)q)[i * 256 + t] = u;
    }
}

extern "C" void kernel_launch(void* const* d_in, const int* in_sizes, int n_in,
                              void* d_out, int out_size, void* d_ws, size_t ws_size,
                              hipStream_t stream)
{
    const float* x  = (const float*)d_in[0];
    const float* Wq = (const float*)d_in[1];
    const float* bq = (const float*)d_in[2];
    const float* Wk = (const float*)d_in[3];
    const float* bk = (const float*)d_in[4];
    const float* Wv = (const float*)d_in[5];
    const float* bv = (const float*)d_in[6];
    float* out = (float*)d_out;

    const int B = 4, S = 4096, H = 1024;
    const size_t MB = 1u << 20;
    if (ws_size < 256 * MB) return;
    char* wsp = (char*)d_ws;

    // ws layout (256 MiB):
    //  [0,64)    x_hi|x_lo (f16)  -> sc fp32 scratch (attn phase)
    //  [64,192)  batch blocks: per batch 32MiB = {qh 8|kh 8|16 dead}; P_b overwrites after softmax_b
    //  [192,224) vT bf16 [1024][16384]
    //  [224,236) W splits (f16 hi/lo x3; lo unused, scratch)
    u16* xh = (u16*)(wsp);
    u16* xl = (u16*)(wsp + 32 * MB);
    float* sc = (float*)(wsp);
    u16* qk = (u16*)(wsp + 64 * MB);
    u16* vT = (u16*)(wsp + 192 * MB);
    u16* Wqh = (u16*)(wsp + 224 * MB), *Wql = (u16*)(wsp + 226 * MB);
    u16* Wkh = (u16*)(wsp + 228 * MB), *Wkl = (u16*)(wsp + 230 * MB);
    u16* Wvh = (u16*)(wsp + 232 * MB), *Wvl = (u16*)(wsp + 234 * MB);

    const dim3 blk(256);
    float* nulf = nullptr;

    hipLaunchKernelGGL(split_h, dim3(B * S * H / 4 / 256), blk, 0, stream, x, xh, xl, B * S * H / 4);
    hipLaunchKernelGGL(split_h, dim3(H * H / 4 / 256), blk, 0, stream, Wq, Wqh, Wql, H * H / 4);
    hipLaunchKernelGGL(split_h, dim3(H * H / 4 / 256), blk, 0, stream, Wk, Wkh, Wkl, H * H / 4);
    hipLaunchKernelGGL(split_h, dim3(H * H / 4 / 256), blk, 0, stream, Wv, Wvh, Wvl, H * H / 4);

    // ---- fused q+k projection: 1024 blocks x 512 thr ----
    hipLaunchKernelGGL(gemm_projqk, dim3(1024), dim3(512), 0, stream,
        xh, xl, Wqh, Wkh, bq, bk,
        qk + 0 * SLOT_E, qk + 1 * SLOT_E);
    // ---- v projection: 128x256 tiles, grid 4 x 128 = 512 ----
    hipLaunchKernelGGL(gemm_projv, dim3(512), dim3(512), 0, stream,
        xh, Wvh, H, H, H, bv,
        nulf, vT, B * S, 4, 0ull, 0ull, 0ull);

    // ---- per-batch scores (1-pass qh·kh, 128x256) + softmax ----
    for (int b = 0; b < B; ++b) {
        const u16* qb = qk + (size_t)b * BBLK_E;
        hipLaunchKernelGGL(gemm_scores, dim3(512), dim3(512), 0, stream,
            qb, qb + SLOT_E,
            H, H, H, (const float*)nullptr,
            sc, (u16*)nullptr, S, 16, 0ull, 0ull, 0ull);
        hipLaunchKernelGGL(softmax4096, dim3(S), blk, 0, stream,
            sc, qk + (size_t)b * BBLK_E);           // P_b overwrites its block
    }

    // ---- batched PV: 128x256 tiles, grid (4 x 32, 1, 4), depth-2 ----
    hipLaunchKernelGGL(gemm_pv, dim3(128, 1, 4), dim3(512), 0, stream,
        qk, vT,
        S, S, B * S, (const float*)nullptr,
        out, (u16*)nullptr, H, 4,
        (unsigned long long)BBLK_E, 4096ull, (unsigned long long)S * H);
}

// Round 16
// 722.444 us; speedup vs baseline: 1.3816x; 1.3816x over previous
//
#include <hip/hip_runtime.h>
#include <math.h>
#include <type_traits>

// SelfAttention B=4,S=4096,H=1024 fp32 — MFMA, fp16-split precision.
// R16 = R14 + (only) PV depth-2. projqk reverted to R14's 1-phase form:
// R15's asm-pinned counted-vmcnt version spilled (12-frag live set > 128 VGPR
// cap -> 622MB scratch writes). Counted-vmcnt only where frags fit (gemm8).

typedef unsigned short u16;
typedef _Float16 f16x8 __attribute__((ext_vector_type(8)));
typedef __bf16 bf16x8 __attribute__((ext_vector_type(8)));
typedef float f32x4 __attribute__((ext_vector_type(4)));
struct __align__(8) u16x4 { u16 x, y, z, w; };

__device__ __forceinline__ u16 f2bf(float f) {
    unsigned u = __builtin_bit_cast(unsigned, f);
    u += 0x7fffu + ((u >> 16) & 1u);
    return (u16)(u >> 16);
}
__device__ __forceinline__ u16 f2h(float f) {
    _Float16 h = (_Float16)f;
    return __builtin_bit_cast(u16, h);
}
__device__ __forceinline__ float h2f(u16 h) {
    return (float)__builtin_bit_cast(_Float16, h);
}

#define MF16(a, b, c) __builtin_amdgcn_mfma_f32_16x16x32_f16( \
    __builtin_bit_cast(f16x8, a), __builtin_bit_cast(f16x8, b), c, 0, 0, 0)
#define MBF16(a, b, c) __builtin_amdgcn_mfma_f32_16x16x32_bf16(a, b, c, 0, 0, 0)

// Batch-blocked q/k/P region geometry (u16 elements).
#define SLOT_E  (4u * 1024 * 1024)        // 8 MiB
#define BBLK_E  (16u * 1024 * 1024)       // 32 MiB per batch block

// ---------------- fused q+k projection (R14 1-phase form, verbatim) ----------------
__global__ __launch_bounds__(512, 4) void gemm_projqk(
    const u16* __restrict__ xh, const u16* __restrict__ xl,
    const u16* __restrict__ Wq, const u16* __restrict__ Wk,
    const float* __restrict__ bq, const float* __restrict__ bk,
    u16* __restrict__ qout, u16* __restrict__ kout)
{
    __shared__ char lds[4 * 8192];
    const int K = 1024, lda = 1024, ldb = 1024, ldc = 1024, nbx = 8;

    const int cpx = (int)gridDim.x >> 3;
    const int raw = blockIdx.x;
    const int swz = (raw & 7) * cpx + (raw >> 3);
    const int bm = (swz / nbx) * 128, bn = (swz % nbx) * 128;

    const int t = threadIdx.x;
    const int w = t >> 6, lane = t & 63;
    const int qksel = w >> 2;
    const int wl = w & 3;
    const int wr = wl >> 1, wc = wl & 1;
    const int r16 = lane & 15, g = lane >> 4;

    f32x4 acc[4][4];
#pragma unroll
    for (int i = 0; i < 4; ++i)
#pragma unroll
        for (int j = 0; j < 4; ++j) acc[i][j] = (f32x4)0.0f;

    for (int k0 = 0; k0 < K; k0 += 32) {
#pragma unroll
        for (int i = 0; i < 4; ++i) {
            const int ch = w * 4 + i;
            const int tt = ch >> 3, sub = ch & 7;
            const int s = sub * 64 + lane;
            const int row = s >> 2;
            const int kg = (s & 3) ^ ((row >> 1) & 3);
            const u16* P = (tt == 0) ? xh : (tt == 1) ? xl : (tt == 2) ? Wq : Wk;
            const int rbase = (tt < 2) ? bm : bn;
            const int ld = (tt < 2) ? lda : ldb;
            __builtin_amdgcn_global_load_lds(
                (const __attribute__((address_space(1))) void*)
                    (P + (size_t)(rbase + row) * ld + k0 + kg * 8),
                (__attribute__((address_space(3))) void*)(lds + ch * 1024),
                16, 0, 0);
        }
        __syncthreads();

        bf16x8 fa[2][4], fb[4];
#pragma unroll
        for (int i = 0; i < 4; ++i) {
            const int ra = wr * 64 + i * 16 + r16;
            const int oa = ra * 64 + ((g ^ ((ra >> 1) & 3)) << 4);
            fa[0][i] = *(const bf16x8*)(lds + oa);
            fa[1][i] = *(const bf16x8*)(lds + 8192 + oa);
            const int rbw = wc * 64 + i * 16 + r16;
            const int ob = rbw * 64 + ((g ^ ((rbw >> 1) & 3)) << 4);
            fb[i] = *(const bf16x8*)(lds + (2 + qksel) * 8192 + ob);
        }
#pragma unroll
        for (int i = 0; i < 4; ++i)
#pragma unroll
            for (int j = 0; j < 4; ++j) {
                acc[i][j] = MF16(fa[0][i], fb[j], acc[i][j]);
                acc[i][j] = MF16(fa[1][i], fb[j], acc[i][j]);
            }
        __syncthreads();
    }

    u16* Cout = qksel ? kout : qout;
    const float* bias = qksel ? bk : bq;
#pragma unroll
    for (int j = 0; j < 4; ++j) {
        const int gc = bn + wc * 64 + j * 16 + r16;
        const float bv = bias[gc];
#pragma unroll
        for (int i = 0; i < 4; ++i) {
            const int gr = bm + wr * 64 + i * 16 + g * 4;
#pragma unroll
            for (int r = 0; r < 4; ++r) {
                const int grr = gr + r;
                const size_t bb = (size_t)(grr >> 12) * BBLK_E;
                Cout[bb + (size_t)(grr & 4095) * ldc + gc] = f2h(acc[i][j][r] + bv);
            }
        }
    }
}

#define GEMM_PARAMS const u16* __restrict__ A0, const u16* __restrict__ B0, \
    int K, int lda, int ldb, const float* __restrict__ bias, \
    float* __restrict__ Cf, u16* __restrict__ Ch, \
    int ldc, int nbx, unsigned long long zsA, unsigned long long zsB, \
    unsigned long long zsC

// ---------- 8-wave 128x256 1-product GEMM, counted-vmcnt depth 1 or 2 ----------
// Buffer = A[128][32] 8KB + B[256][32] 16KB = 24KB. Stage = 3 loads/wave.
// DEPTH=1: 2 buffers, vmcnt(3). DEPTH=2: 3 buffers, vmcnt(6), tail vmcnt(3)/0.
// Frag live set = 8x bf16x8 (32 VGPR) + 64 acc -> fits LB(512,4) cap, no spill.
template<int VAR, int DEPTH>  // VAR 1: projv f16->bf16^T+bias; 2: scores f16->f32; 3: pv bf16->f32
__device__ __forceinline__ void gemm8_body(GEMM_PARAMS)
{
    __shared__ char lds[(DEPTH + 1) * 24576];

    const int cpx = (int)gridDim.x >> 3;
    const int raw = blockIdx.x;
    const int swz = (raw & 7) * cpx + (raw >> 3);
    const int bm = (swz / nbx) * 128, bn = (swz % nbx) * 256;

    const unsigned long long z = blockIdx.z;
    A0 += z * zsA;
    B0 += z * zsB;

    const int t = threadIdx.x;
    const int w = t >> 6, lane = t & 63;
    const int wr = w >> 2, wc = w & 3;
    const int r16 = lane & 15, g = lane >> 4;

    f32x4 acc[4][4];
#pragma unroll
    for (int i = 0; i < 4; ++i)
#pragma unroll
        for (int j = 0; j < 4; ++j) acc[i][j] = (f32x4)0.0f;

    auto STAGE = [&](auto BO, int k0) {
#pragma unroll
        for (int i = 0; i < 3; ++i) {
            constexpr int bufo = decltype(BO)::value;
            const int ch = w * 3 + i;             // 0..23; 0-7 A, 8-23 B
            const int isB = (ch >= 8);
            const int cb = isB ? (ch - 8) : ch;
            const int row = cb * 16 + (lane >> 2);
            const int kg = (lane & 3) ^ ((row >> 1) & 3);
            const u16* P = isB ? B0 : A0;
            const int rbase = isB ? bn : bm;
            const int ld = isB ? ldb : lda;
            __builtin_amdgcn_global_load_lds(
                (const __attribute__((address_space(1))) void*)
                    (P + (size_t)(rbase + row) * ld + k0 + kg * 8),
                (__attribute__((address_space(3))) void*)
                    (lds + bufo + (isB ? 8192 : 0) + cb * 1024),
                16, 0, 0);
        }
    };

    bf16x8 fa[4], fb[4];
    auto FRAGS = [&](auto BO) {
        constexpr int bufo = decltype(BO)::value;
#pragma unroll
        for (int i = 0; i < 4; ++i) {
            const int ra = wr * 64 + i * 16 + r16;
            fa[i] = *(const bf16x8*)(lds + bufo + ra * 64 + ((g ^ ((ra >> 1) & 3)) << 4));
            const int rb = wc * 64 + i * 16 + r16;
            fb[i] = *(const bf16x8*)(lds + bufo + 8192 + rb * 64 + ((g ^ ((rb >> 1) & 3)) << 4));
        }
    };
    auto MM = [&]() {
#pragma unroll
        for (int i = 0; i < 4; ++i)
#pragma unroll
            for (int j = 0; j < 4; ++j) {
                if constexpr (VAR == 3) acc[i][j] = MBF16(fa[i], fb[j], acc[i][j]);
                else                    acc[i][j] = MF16(fa[i], fb[j], acc[i][j]);
            }
    };

    std::integral_constant<int, 0> c0;
    std::integral_constant<int, 24576> c1;
    std::integral_constant<int, 49152> c2;

    const int nk = K >> 5;                 // 32 (projv/scores) or 128 (pv)

    if constexpr (DEPTH == 1) {
        STAGE(c0, 0);
        STAGE(c1, 1 << 5);
        for (int tt = 0; tt + 2 < nk; tt += 2) {
            asm volatile("s_waitcnt vmcnt(3)\n\ts_barrier" ::: "memory");
            FRAGS(c0);
            asm volatile("s_waitcnt lgkmcnt(0)\n\ts_barrier" ::: "memory");
            STAGE(c0, (tt + 2) << 5);
            MM();
            asm volatile("s_waitcnt vmcnt(3)\n\ts_barrier" ::: "memory");
            FRAGS(c1);
            asm volatile("s_waitcnt lgkmcnt(0)\n\ts_barrier" ::: "memory");
            STAGE(c1, (tt + 3) << 5);
            MM();
        }
        asm volatile("s_waitcnt vmcnt(3)\n\ts_barrier" ::: "memory");
        FRAGS(c0);
        MM();
        asm volatile("s_waitcnt vmcnt(0)\n\ts_barrier" ::: "memory");
        FRAGS(c1);
        MM();
    } else {
        // depth-2: 3 buffers; steady outstanding = 2 stages = 6 loads.
        STAGE(c0, 0);
        STAGE(c1, 1 << 5);
        STAGE(c2, 2 << 5);
        for (int tt = 0; tt + 4 < nk; tt += 3) {
            asm volatile("s_waitcnt vmcnt(6)\n\ts_barrier" ::: "memory");
            FRAGS(c0);
            asm volatile("s_waitcnt lgkmcnt(0)\n\ts_barrier" ::: "memory");
            STAGE(c0, (tt + 3) << 5);
            MM();
            asm volatile("s_waitcnt vmcnt(6)\n\ts_barrier" ::: "memory");
            FRAGS(c1);
            asm volatile("s_waitcnt lgkmcnt(0)\n\ts_barrier" ::: "memory");
            STAGE(c1, (tt + 4) << 5);
            MM();
            asm volatile("s_waitcnt vmcnt(6)\n\ts_barrier" ::: "memory");
            FRAGS(c2);
            asm volatile("s_waitcnt lgkmcnt(0)\n\ts_barrier" ::: "memory");
            if (tt + 5 < nk) STAGE(c2, (tt + 5) << 5);
            MM();
        }
        // tail: iters nk-2 (c0; stage nk-1 = 3 loads in flight), nk-1 (c1)
        asm volatile("s_waitcnt vmcnt(3)\n\ts_barrier" ::: "memory");
        FRAGS(c0);
        MM();
        asm volatile("s_waitcnt vmcnt(0)\n\ts_barrier" ::: "memory");
        FRAGS(c1);
        MM();
    }

    // ---- epilogue: C/D layout col=lane&15, row=(lane>>4)*4+reg ----
#pragma unroll
    for (int j = 0; j < 4; ++j) {
        const int gc = bn + wc * 64 + j * 16 + r16;
        const float bv = bias ? bias[gc] : 0.0f;
#pragma unroll
        for (int i = 0; i < 4; ++i) {
            const int gr = bm + wr * 64 + i * 16 + g * 4;
#pragma unroll
            for (int r = 0; r < 4; ++r) {
                const float val = acc[i][j][r] + bv;
                const int grr = gr + r;
                if constexpr (VAR == 1) {
                    Ch[(size_t)gc * ldc + grr] = f2bf(val);   // transposed
                } else {
                    Cf[z * zsC + (size_t)grr * ldc + gc] = val;
                }
            }
        }
    }
}

__global__ __launch_bounds__(512, 4) void gemm_projv(GEMM_PARAMS) { gemm8_body<1, 1>(A0,B0,K,lda,ldb,bias,Cf,Ch,ldc,nbx,zsA,zsB,zsC); }
__global__ __launch_bounds__(512, 4) void gemm_scores(GEMM_PARAMS){ gemm8_body<2, 1>(A0,B0,K,lda,ldb,bias,Cf,Ch,ldc,nbx,zsA,zsB,zsC); }
__global__ __launch_bounds__(512, 4) void gemm_pv(GEMM_PARAMS)    { gemm8_body<3, 2>(A0,B0,K,lda,ldb,bias,Cf,Ch,ldc,nbx,zsA,zsB,zsC); }

// fp32 -> fp16 (hi, lo) elementwise over float4 groups.
__global__ __launch_bounds__(256) void split_h(
    const float* __restrict__ in, u16* __restrict__ hi, u16* __restrict__ lo, int n4)
{
    const int i = blockIdx.x * 256 + threadIdx.x;
    if (i >= n4) return;
    const float4 v = ((const float4*)in)[i];
    u16x4 h, l;
    h.x = f2h(v.x); l.x = f2h(v.x - h2f(h.x));
    h.y = f2h(v.y); l.y = f2h(v.y - h2f(h.y));
    h.z = f2h(v.z); l.z = f2h(v.z - h2f(h.z));
    h.w = f2h(v.w); l.w = f2h(v.w - h2f(h.w));
    ((u16x4*)hi)[i] = h;
    ((u16x4*)lo)[i] = l;
}

// Row softmax over 4096 fp32 -> bf16 P. One 256-thread block per row.
__global__ __launch_bounds__(256) void softmax4096(
    const float* __restrict__ S, u16* __restrict__ P)
{
    const float* p = S + (size_t)blockIdx.x * 4096;
    u16* q = P + (size_t)blockIdx.x * 4096;
    const int t = threadIdx.x;
    const int wave = t >> 6, lane = t & 63;
    __shared__ float red[8];

    float4 v[4];
    float mx = -INFINITY;
#pragma unroll
    for (int i = 0; i < 4; ++i) {
        v[i] = ((const float4*)p)[i * 256 + t];
        mx = fmaxf(mx, fmaxf(fmaxf(v[i].x, v[i].y), fmaxf(v[i].z, v[i].w)));
    }
#pragma unroll
    for (int o = 32; o > 0; o >>= 1) mx = fmaxf(mx, __shfl_xor(mx, o));
    if (lane == 0) red[wave] = mx;
    __syncthreads();
    mx = fmaxf(fmaxf(red[0], red[1]), fmaxf(red[2], red[3]));

    float sum = 0.f;
#pragma unroll
    for (int i = 0; i < 4; ++i) {
        v[i].x = __expf(v[i].x - mx);
        v[i].y = __expf(v[i].y - mx);
        v[i].z = __expf(v[i].z - mx);
        v[i].w = __expf(v[i].w - mx);
        sum += (v[i].x + v[i].y) + (v[i].z + v[i].w);
    }
#pragma unroll
    for (int o = 32; o > 0; o >>= 1) sum += __shfl_xor(sum, o);
    if (lane == 0) red[4 + wave] = sum;
    __syncthreads();
    sum = (red[4] + red[5]) + (red[6] + red[7]);

    const float inv = 1.0f / sum;
#pragma unroll
    for (int i = 0; i < 4; ++i) {
        u16x4 u;
        u.x = f2bf(v[i].x * inv); u.y = f2bf(v[i].y * inv);
        u.z = f2bf(v[i].z * inv); u.w = f2bf(v[i].w * inv);
        ((u16x4*)q)[i * 256 + t] = u;
    }
}

extern "C" void kernel_launch(void* const* d_in, const int* in_sizes, int n_in,
                              void* d_out, int out_size, void* d_ws, size_t ws_size,
                              hipStream_t stream)
{
    const float* x  = (const float*)d_in[0];
    const float* Wq = (const float*)d_in[1];
    const float* bq = (const float*)d_in[2];
    const float* Wk = (const float*)d_in[3];
    const float* bk = (const float*)d_in[4];
    const float* Wv = (const float*)d_in[5];
    const float* bv = (const float*)d_in[6];
    float* out = (float*)d_out;

    const int B = 4, S = 4096, H = 1024;
    const size_t MB = 1u << 20;
    if (ws_size < 256 * MB) return;
    char* wsp = (char*)d_ws;

    // ws layout (256 MiB):
    //  [0,64)    x_hi|x_lo (f16)  -> sc fp32 scratch (attn phase)
    //  [64,192)  batch blocks: per batch 32MiB = {qh 8|kh 8|16 dead}; P_b overwrites after softmax_b
    //  [192,224) vT bf16 [1024][16384]
    //  [224,236) W splits (f16 hi/lo x3; lo unused, scratch)
    u16* xh = (u16*)(wsp);
    u16* xl = (u16*)(wsp + 32 * MB);
    float* sc = (float*)(wsp);
    u16* qk = (u16*)(wsp + 64 * MB);
    u16* vT = (u16*)(wsp + 192 * MB);
    u16* Wqh = (u16*)(wsp + 224 * MB), *Wql = (u16*)(wsp + 226 * MB);
    u16* Wkh = (u16*)(wsp + 228 * MB), *Wkl = (u16*)(wsp + 230 * MB);
    u16* Wvh = (u16*)(wsp + 232 * MB), *Wvl = (u16*)(wsp + 234 * MB);

    const dim3 blk(256);
    float* nulf = nullptr;

    hipLaunchKernelGGL(split_h, dim3(B * S * H / 4 / 256), blk, 0, stream, x, xh, xl, B * S * H / 4);
    hipLaunchKernelGGL(split_h, dim3(H * H / 4 / 256), blk, 0, stream, Wq, Wqh, Wql, H * H / 4);
    hipLaunchKernelGGL(split_h, dim3(H * H / 4 / 256), blk, 0, stream, Wk, Wkh, Wkl, H * H / 4);
    hipLaunchKernelGGL(split_h, dim3(H * H / 4 / 256), blk, 0, stream, Wv, Wvh, Wvl, H * H / 4);

    // ---- fused q+k projection: 1024 blocks x 512 thr (R14 form) ----
    hipLaunchKernelGGL(gemm_projqk, dim3(1024), dim3(512), 0, stream,
        xh, xl, Wqh, Wkh, bq, bk,
        qk + 0 * SLOT_E, qk + 1 * SLOT_E);
    // ---- v projection: 128x256 tiles, grid 4 x 128 = 512 ----
    hipLaunchKernelGGL(gemm_projv, dim3(512), dim3(512), 0, stream,
        xh, Wvh, H, H, H, bv,
        nulf, vT, B * S, 4, 0ull, 0ull, 0ull);

    // ---- per-batch scores (1-pass qh·kh, 128x256) + softmax ----
    for (int b = 0; b < B; ++b) {
        const u16* qb = qk + (size_t)b * BBLK_E;
        hipLaunchKernelGGL(gemm_scores, dim3(512), dim3(512), 0, stream,
            qb, qb + SLOT_E,
            H, H, H, (const float*)nullptr,
            sc, (u16*)nullptr, S, 16, 0ull, 0ull, 0ull);
        hipLaunchKernelGGL(softmax4096, dim3(S), blk, 0, stream,
            sc, qk + (size_t)b * BBLK_E);           // P_b overwrites its block
    }

    // ---- batched PV: 128x256 tiles, grid (4 x 32, 1, 4), depth-2 ----
    hipLaunchKernelGGL(gemm_pv, dim3(128, 1, 4), dim3(512), 0, stream,
        qk, vT,
        S, S, B * S, (const float*)nullptr,
        out, (u16*)nullptr, H, 4,
        (unsigned long long)BBLK_E, 4096ull, (unsigned long long)S * H);
}

// Round 17
// 559.741 us; speedup vs baseline: 1.7832x; 1.2907x over previous
//
#include <hip/hip_runtime.h>
#include <math.h>
#include <type_traits>

// SelfAttention B=4,S=4096,H=1024 fp32 — MFMA, fp16-split precision.
// R17 = R14 exact config (PV back to depth-1). R16 isolated PV-depth-2 as the
// regressor: 72KB LDS -> 2 blk/CU + distance-3 prefetch stretched vT reuse
// past L2 -> FETCH 220->586MB. Depth-1 counted-vmcnt is optimal everywhere.

typedef unsigned short u16;
typedef _Float16 f16x8 __attribute__((ext_vector_type(8)));
typedef __bf16 bf16x8 __attribute__((ext_vector_type(8)));
typedef float f32x4 __attribute__((ext_vector_type(4)));
struct __align__(8) u16x4 { u16 x, y, z, w; };

__device__ __forceinline__ u16 f2bf(float f) {
    unsigned u = __builtin_bit_cast(unsigned, f);
    u += 0x7fffu + ((u >> 16) & 1u);
    return (u16)(u >> 16);
}
__device__ __forceinline__ u16 f2h(float f) {
    _Float16 h = (_Float16)f;
    return __builtin_bit_cast(u16, h);
}
__device__ __forceinline__ float h2f(u16 h) {
    return (float)__builtin_bit_cast(_Float16, h);
}

#define MF16(a, b, c) __builtin_amdgcn_mfma_f32_16x16x32_f16( \
    __builtin_bit_cast(f16x8, a), __builtin_bit_cast(f16x8, b), c, 0, 0, 0)
#define MBF16(a, b, c) __builtin_amdgcn_mfma_f32_16x16x32_bf16(a, b, c, 0, 0, 0)

// Batch-blocked q/k/P region geometry (u16 elements).
#define SLOT_E  (4u * 1024 * 1024)        // 8 MiB
#define BBLK_E  (16u * 1024 * 1024)       // 32 MiB per batch block

// ---------------- fused q+k projection (R14 1-phase form) ----------------
__global__ __launch_bounds__(512, 4) void gemm_projqk(
    const u16* __restrict__ xh, const u16* __restrict__ xl,
    const u16* __restrict__ Wq, const u16* __restrict__ Wk,
    const float* __restrict__ bq, const float* __restrict__ bk,
    u16* __restrict__ qout, u16* __restrict__ kout)
{
    __shared__ char lds[4 * 8192];
    const int K = 1024, lda = 1024, ldb = 1024, ldc = 1024, nbx = 8;

    const int cpx = (int)gridDim.x >> 3;
    const int raw = blockIdx.x;
    const int swz = (raw & 7) * cpx + (raw >> 3);
    const int bm = (swz / nbx) * 128, bn = (swz % nbx) * 128;

    const int t = threadIdx.x;
    const int w = t >> 6, lane = t & 63;
    const int qksel = w >> 2;
    const int wl = w & 3;
    const int wr = wl >> 1, wc = wl & 1;
    const int r16 = lane & 15, g = lane >> 4;

    f32x4 acc[4][4];
#pragma unroll
    for (int i = 0; i < 4; ++i)
#pragma unroll
        for (int j = 0; j < 4; ++j) acc[i][j] = (f32x4)0.0f;

    for (int k0 = 0; k0 < K; k0 += 32) {
#pragma unroll
        for (int i = 0; i < 4; ++i) {
            const int ch = w * 4 + i;
            const int tt = ch >> 3, sub = ch & 7;
            const int s = sub * 64 + lane;
            const int row = s >> 2;
            const int kg = (s & 3) ^ ((row >> 1) & 3);
            const u16* P = (tt == 0) ? xh : (tt == 1) ? xl : (tt == 2) ? Wq : Wk;
            const int rbase = (tt < 2) ? bm : bn;
            const int ld = (tt < 2) ? lda : ldb;
            __builtin_amdgcn_global_load_lds(
                (const __attribute__((address_space(1))) void*)
                    (P + (size_t)(rbase + row) * ld + k0 + kg * 8),
                (__attribute__((address_space(3))) void*)(lds + ch * 1024),
                16, 0, 0);
        }
        __syncthreads();

        bf16x8 fa[2][4], fb[4];
#pragma unroll
        for (int i = 0; i < 4; ++i) {
            const int ra = wr * 64 + i * 16 + r16;
            const int oa = ra * 64 + ((g ^ ((ra >> 1) & 3)) << 4);
            fa[0][i] = *(const bf16x8*)(lds + oa);
            fa[1][i] = *(const bf16x8*)(lds + 8192 + oa);
            const int rbw = wc * 64 + i * 16 + r16;
            const int ob = rbw * 64 + ((g ^ ((rbw >> 1) & 3)) << 4);
            fb[i] = *(const bf16x8*)(lds + (2 + qksel) * 8192 + ob);
        }
#pragma unroll
        for (int i = 0; i < 4; ++i)
#pragma unroll
            for (int j = 0; j < 4; ++j) {
                acc[i][j] = MF16(fa[0][i], fb[j], acc[i][j]);
                acc[i][j] = MF16(fa[1][i], fb[j], acc[i][j]);
            }
        __syncthreads();
    }

    u16* Cout = qksel ? kout : qout;
    const float* bias = qksel ? bk : bq;
#pragma unroll
    for (int j = 0; j < 4; ++j) {
        const int gc = bn + wc * 64 + j * 16 + r16;
        const float bv = bias[gc];
#pragma unroll
        for (int i = 0; i < 4; ++i) {
            const int gr = bm + wr * 64 + i * 16 + g * 4;
#pragma unroll
            for (int r = 0; r < 4; ++r) {
                const int grr = gr + r;
                const size_t bb = (size_t)(grr >> 12) * BBLK_E;
                Cout[bb + (size_t)(grr & 4095) * ldc + gc] = f2h(acc[i][j][r] + bv);
            }
        }
    }
}

#define GEMM_PARAMS const u16* __restrict__ A0, const u16* __restrict__ B0, \
    int K, int lda, int ldb, const float* __restrict__ bias, \
    float* __restrict__ Cf, u16* __restrict__ Ch, \
    int ldc, int nbx, unsigned long long zsA, unsigned long long zsB, \
    unsigned long long zsC

// ---------- 8-wave 128x256 1-product GEMM, counted-vmcnt depth-1 ----------
// Buffer = A[128][32] 8KB + B[256][32] 16KB = 24KB; 2 buffers = 48KB.
// Stage = 3 loads/wave -> vmcnt(3) steady state.
template<int VAR>  // VAR 1: projv f16->bf16^T+bias; 2: scores f16->f32; 3: pv bf16->f32
__device__ __forceinline__ void gemm8_body(GEMM_PARAMS)
{
    __shared__ char lds[2 * 24576];

    const int cpx = (int)gridDim.x >> 3;
    const int raw = blockIdx.x;
    const int swz = (raw & 7) * cpx + (raw >> 3);
    const int bm = (swz / nbx) * 128, bn = (swz % nbx) * 256;

    const unsigned long long z = blockIdx.z;
    A0 += z * zsA;
    B0 += z * zsB;

    const int t = threadIdx.x;
    const int w = t >> 6, lane = t & 63;
    const int wr = w >> 2, wc = w & 3;
    const int r16 = lane & 15, g = lane >> 4;

    f32x4 acc[4][4];
#pragma unroll
    for (int i = 0; i < 4; ++i)
#pragma unroll
        for (int j = 0; j < 4; ++j) acc[i][j] = (f32x4)0.0f;

    auto STAGE = [&](auto BO, int k0) {
#pragma unroll
        for (int i = 0; i < 3; ++i) {
            constexpr int bufo = decltype(BO)::value;
            const int ch = w * 3 + i;             // 0..23; 0-7 A, 8-23 B
            const int isB = (ch >= 8);
            const int cb = isB ? (ch - 8) : ch;
            const int row = cb * 16 + (lane >> 2);
            const int kg = (lane & 3) ^ ((row >> 1) & 3);
            const u16* P = isB ? B0 : A0;
            const int rbase = isB ? bn : bm;
            const int ld = isB ? ldb : lda;
            __builtin_amdgcn_global_load_lds(
                (const __attribute__((address_space(1))) void*)
                    (P + (size_t)(rbase + row) * ld + k0 + kg * 8),
                (__attribute__((address_space(3))) void*)
                    (lds + bufo + (isB ? 8192 : 0) + cb * 1024),
                16, 0, 0);
        }
    };

    bf16x8 fa[4], fb[4];
    auto FRAGS = [&](auto BO) {
        constexpr int bufo = decltype(BO)::value;
#pragma unroll
        for (int i = 0; i < 4; ++i) {
            const int ra = wr * 64 + i * 16 + r16;
            fa[i] = *(const bf16x8*)(lds + bufo + ra * 64 + ((g ^ ((ra >> 1) & 3)) << 4));
            const int rb = wc * 64 + i * 16 + r16;
            fb[i] = *(const bf16x8*)(lds + bufo + 8192 + rb * 64 + ((g ^ ((rb >> 1) & 3)) << 4));
        }
    };
    auto MM = [&]() {
#pragma unroll
        for (int i = 0; i < 4; ++i)
#pragma unroll
            for (int j = 0; j < 4; ++j) {
                if constexpr (VAR == 3) acc[i][j] = MBF16(fa[i], fb[j], acc[i][j]);
                else                    acc[i][j] = MF16(fa[i], fb[j], acc[i][j]);
            }
    };

    std::integral_constant<int, 0> c0;
    std::integral_constant<int, 24576> c1;

    const int nk = K >> 5;                 // 32 (projv/scores) or 128 (pv); even
    STAGE(c0, 0);
    STAGE(c1, 1 << 5);
    for (int tt = 0; tt + 2 < nk; tt += 2) {
        asm volatile("s_waitcnt vmcnt(3)\n\ts_barrier" ::: "memory");
        FRAGS(c0);
        asm volatile("s_waitcnt lgkmcnt(0)\n\ts_barrier" ::: "memory");
        STAGE(c0, (tt + 2) << 5);
        MM();
        asm volatile("s_waitcnt vmcnt(3)\n\ts_barrier" ::: "memory");
        FRAGS(c1);
        asm volatile("s_waitcnt lgkmcnt(0)\n\ts_barrier" ::: "memory");
        STAGE(c1, (tt + 3) << 5);
        MM();
    }
    asm volatile("s_waitcnt vmcnt(3)\n\ts_barrier" ::: "memory");
    FRAGS(c0);
    MM();
    asm volatile("s_waitcnt vmcnt(0)\n\ts_barrier" ::: "memory");
    FRAGS(c1);
    MM();

    // ---- epilogue: C/D layout col=lane&15, row=(lane>>4)*4+reg ----
#pragma unroll
    for (int j = 0; j < 4; ++j) {
        const int gc = bn + wc * 64 + j * 16 + r16;
        const float bv = bias ? bias[gc] : 0.0f;
#pragma unroll
        for (int i = 0; i < 4; ++i) {
            const int gr = bm + wr * 64 + i * 16 + g * 4;
#pragma unroll
            for (int r = 0; r < 4; ++r) {
                const float val = acc[i][j][r] + bv;
                const int grr = gr + r;
                if constexpr (VAR == 1) {
                    Ch[(size_t)gc * ldc + grr] = f2bf(val);   // transposed
                } else {
                    Cf[z * zsC + (size_t)grr * ldc + gc] = val;
                }
            }
        }
    }
}

__global__ __launch_bounds__(512, 4) void gemm_projv(GEMM_PARAMS) { gemm8_body<1>(A0,B0,K,lda,ldb,bias,Cf,Ch,ldc,nbx,zsA,zsB,zsC); }
__global__ __launch_bounds__(512, 4) void gemm_scores(GEMM_PARAMS){ gemm8_body<2>(A0,B0,K,lda,ldb,bias,Cf,Ch,ldc,nbx,zsA,zsB,zsC); }
__global__ __launch_bounds__(512, 4) void gemm_pv(GEMM_PARAMS)    { gemm8_body<3>(A0,B0,K,lda,ldb,bias,Cf,Ch,ldc,nbx,zsA,zsB,zsC); }

// fp32 -> fp16 (hi, lo) elementwise over float4 groups.
__global__ __launch_bounds__(256) void split_h(
    const float* __restrict__ in, u16* __restrict__ hi, u16* __restrict__ lo, int n4)
{
    const int i = blockIdx.x * 256 + threadIdx.x;
    if (i >= n4) return;
    const float4 v = ((const float4*)in)[i];
    u16x4 h, l;
    h.x = f2h(v.x); l.x = f2h(v.x - h2f(h.x));
    h.y = f2h(v.y); l.y = f2h(v.y - h2f(h.y));
    h.z = f2h(v.z); l.z = f2h(v.z - h2f(h.z));
    h.w = f2h(v.w); l.w = f2h(v.w - h2f(h.w));
    ((u16x4*)hi)[i] = h;
    ((u16x4*)lo)[i] = l;
}

// Row softmax over 4096 fp32 -> bf16 P. One 256-thread block per row.
__global__ __launch_bounds__(256) void softmax4096(
    const float* __restrict__ S, u16* __restrict__ P)
{
    const float* p = S + (size_t)blockIdx.x * 4096;
    u16* q = P + (size_t)blockIdx.x * 4096;
    const int t = threadIdx.x;
    const int wave = t >> 6, lane = t & 63;
    __shared__ float red[8];

    float4 v[4];
    float mx = -INFINITY;
#pragma unroll
    for (int i = 0; i < 4; ++i) {
        v[i] = ((const float4*)p)[i * 256 + t];
        mx = fmaxf(mx, fmaxf(fmaxf(v[i].x, v[i].y), fmaxf(v[i].z, v[i].w)));
    }
#pragma unroll
    for (int o = 32; o > 0; o >>= 1) mx = fmaxf(mx, __shfl_xor(mx, o));
    if (lane == 0) red[wave] = mx;
    __syncthreads();
    mx = fmaxf(fmaxf(red[0], red[1]), fmaxf(red[2], red[3]));

    float sum = 0.f;
#pragma unroll
    for (int i = 0; i < 4; ++i) {
        v[i].x = __expf(v[i].x - mx);
        v[i].y = __expf(v[i].y - mx);
        v[i].z = __expf(v[i].z - mx);
        v[i].w = __expf(v[i].w - mx);
        sum += (v[i].x + v[i].y) + (v[i].z + v[i].w);
    }
#pragma unroll
    for (int o = 32; o > 0; o >>= 1) sum += __shfl_xor(sum, o);
    if (lane == 0) red[4 + wave] = sum;
    __syncthreads();
    sum = (red[4] + red[5]) + (red[6] + red[7]);

    const float inv = 1.0f / sum;
#pragma unroll
    for (int i = 0; i < 4; ++i) {
        u16x4 u;
        u.x = f2bf(v[i].x * inv); u.y = f2bf(v[i].y * inv);
        u.z = f2bf(v[i].z * inv); u.w = f2bf(v[i].w * inv);
        ((u16x4*)q)[i * 256 + t] = u;
    }
}

extern "C" void kernel_launch(void* const* d_in, const int* in_sizes, int n_in,
                              void* d_out, int out_size, void* d_ws, size_t ws_size,
                              hipStream_t stream)
{
    const float* x  = (const float*)d_in[0];
    const float* Wq = (const float*)d_in[1];
    const float* bq = (const float*)d_in[2];
    const float* Wk = (const float*)d_in[3];
    const float* bk = (const float*)d_in[4];
    const float* Wv = (const float*)d_in[5];
    const float* bv = (const float*)d_in[6];
    float* out = (float*)d_out;

    const int B = 4, S = 4096, H = 1024;
    const size_t MB = 1u << 20;
    if (ws_size < 256 * MB) return;
    char* wsp = (char*)d_ws;

    // ws layout (256 MiB):
    //  [0,64)    x_hi|x_lo (f16)  -> sc fp32 scratch (attn phase)
    //  [64,192)  batch blocks: per batch 32MiB = {qh 8|kh 8|16 dead}; P_b overwrites after softmax_b
    //  [192,224) vT bf16 [1024][16384]
    //  [224,236) W splits (f16 hi/lo x3; lo unused, scratch)
    u16* xh = (u16*)(wsp);
    u16* xl = (u16*)(wsp + 32 * MB);
    float* sc = (float*)(wsp);
    u16* qk = (u16*)(wsp + 64 * MB);
    u16* vT = (u16*)(wsp + 192 * MB);
    u16* Wqh = (u16*)(wsp + 224 * MB), *Wql = (u16*)(wsp + 226 * MB);
    u16* Wkh = (u16*)(wsp + 228 * MB), *Wkl = (u16*)(wsp + 230 * MB);
    u16* Wvh = (u16*)(wsp + 232 * MB), *Wvl = (u16*)(wsp + 234 * MB);

    const dim3 blk(256);
    float* nulf = nullptr;

    hipLaunchKernelGGL(split_h, dim3(B * S * H / 4 / 256), blk, 0, stream, x, xh, xl, B * S * H / 4);
    hipLaunchKernelGGL(split_h, dim3(H * H / 4 / 256), blk, 0, stream, Wq, Wqh, Wql, H * H / 4);
    hipLaunchKernelGGL(split_h, dim3(H * H / 4 / 256), blk, 0, stream, Wk, Wkh, Wkl, H * H / 4);
    hipLaunchKernelGGL(split_h, dim3(H * H / 4 / 256), blk, 0, stream, Wv, Wvh, Wvl, H * H / 4);

    // ---- fused q+k projection: 1024 blocks x 512 thr ----
    hipLaunchKernelGGL(gemm_projqk, dim3(1024), dim3(512), 0, stream,
        xh, xl, Wqh, Wkh, bq, bk,
        qk + 0 * SLOT_E, qk + 1 * SLOT_E);
    // ---- v projection: 128x256 tiles, grid 4 x 128 = 512 ----
    hipLaunchKernelGGL(gemm_projv, dim3(512), dim3(512), 0, stream,
        xh, Wvh, H, H, H, bv,
        nulf, vT, B * S, 4, 0ull, 0ull, 0ull);

    // ---- per-batch scores (1-pass qh·kh, 128x256) + softmax ----
    for (int b = 0; b < B; ++b) {
        const u16* qb = qk + (size_t)b * BBLK_E;
        hipLaunchKernelGGL(gemm_scores, dim3(512), dim3(512), 0, stream,
            qb, qb + SLOT_E,
            H, H, H, (const float*)nullptr,
            sc, (u16*)nullptr, S, 16, 0ull, 0ull, 0ull);
        hipLaunchKernelGGL(softmax4096, dim3(S), blk, 0, stream,
            sc, qk + (size_t)b * BBLK_E);           // P_b overwrites its block
    }

    // ---- batched PV: 128x256 tiles, grid (4 x 32, 1, 4), depth-1 ----
    hipLaunchKernelGGL(gemm_pv, dim3(128, 1, 4), dim3(512), 0, stream,
        qk, vT,
        S, S, B * S, (const float*)nullptr,
        out, (u16*)nullptr, H, 4,
        (unsigned long long)BBLK_E, 4096ull, (unsigned long long)S * H);
}